// Round 1
// baseline (116.221 us; speedup 1.0000x reference)
//
#include <hip/hip_runtime.h>

typedef __attribute__((ext_vector_type(8))) short short8;
typedef __attribute__((ext_vector_type(4))) float f32x4;

#define TANH_SCALE 2.8853900817779268f  /* 2*log2(e): exp(2x) = exp2(x*TANH_SCALE) */

static __device__ __forceinline__ unsigned short f2bf(float f) {
  unsigned u = __builtin_bit_cast(unsigned, f);
  u += 0x7FFFu + ((u >> 16) & 1u);   // round-to-nearest-even
  return (unsigned short)(u >> 16);
}

// fp32 -> bf16, 4 elements/thread (all tensor sizes are multiples of 4)
__global__ void cvt_bf16x4(const float4* __restrict__ src, ushort4* __restrict__ dst, int n4) {
  int i = blockIdx.x * blockDim.x + threadIdx.x;
  if (i >= n4) return;
  float4 v = src[i];
  ushort4 o;
  o.x = f2bf(v.x); o.y = f2bf(v.y); o.z = f2bf(v.z); o.w = f2bf(v.w);
  dst[i] = o;
}

// vt2[l] = 2*vt[l]  (the 2 from tanh = 1 - 2*rcp(e^{2x}+1); the Sum(vt) constant is
// dropped entirely: it is uniform over s, so log_softmax is invariant to it)
__global__ void scale_vt(const float* __restrict__ vt, float* __restrict__ vt2, int n) {
  int i = blockIdx.x * blockDim.x + threadIdx.x;
  if (i < n) vt2[i] = 2.0f * vt[i];
}

// NT GEMM: C[m][n] = scale * sum_k A[m][k]*B[n][k].  A: MxK bf16 rm, B: NxK bf16 rm,
// C: MxN fp32 rm. Batched via blockIdx.z with element strides. M%64==0, N%64==0, K%32==0.
// Block = 4 waves; wave w computes rows [m0+16w, m0+16w+16) x cols [n0, n0+64).
__global__ __launch_bounds__(256) void gemm_nt_bf16(
    const unsigned short* __restrict__ A, const unsigned short* __restrict__ B,
    float* __restrict__ C, int M, int N, int K,
    long sA, long sB, long sC, float scale) {
  A += (long)blockIdx.z * sA;
  B += (long)blockIdx.z * sB;
  C += (long)blockIdx.z * sC;
  const int tid = threadIdx.x, wave = tid >> 6, lane = tid & 63;
  const int m0 = blockIdx.x * 64 + wave * 16;
  const int n0 = blockIdx.y * 64;
  const int l16 = lane & 15, quad = lane >> 4, kb = quad * 8;
  const int mrow = m0 + l16;

  f32x4 acc0 = {0.f, 0.f, 0.f, 0.f};
  f32x4 acc1 = {0.f, 0.f, 0.f, 0.f};
  f32x4 acc2 = {0.f, 0.f, 0.f, 0.f};
  f32x4 acc3 = {0.f, 0.f, 0.f, 0.f};

  const unsigned short* ap = A + (long)mrow * K + kb;
  const unsigned short* bp0 = B + (long)(n0 + l16) * K + kb;

  for (int ks = 0; ks < K; ks += 32) {
    short8 a = *(const short8*)(ap + ks);
    short8 b0 = *(const short8*)(bp0 + ks);
    short8 b1 = *(const short8*)(bp0 + 16 * K + ks);
    short8 b2 = *(const short8*)(bp0 + 32 * K + ks);
    short8 b3 = *(const short8*)(bp0 + 48 * K + ks);
    acc0 = __builtin_amdgcn_mfma_f32_16x16x32_bf16(a, b0, acc0, 0, 0, 0);
    acc1 = __builtin_amdgcn_mfma_f32_16x16x32_bf16(a, b1, acc1, 0, 0, 0);
    acc2 = __builtin_amdgcn_mfma_f32_16x16x32_bf16(a, b2, acc2, 0, 0, 0);
    acc3 = __builtin_amdgcn_mfma_f32_16x16x32_bf16(a, b3, acc3, 0, 0, 0);
  }

  // C/D layout (verified m89/m91): col = lane&15, row = quad*4 + reg
  f32x4 accs[4] = {acc0, acc1, acc2, acc3};
#pragma unroll
  for (int j = 0; j < 4; ++j) {
    int n = n0 + j * 16 + l16;
#pragma unroll
    for (int r = 0; r < 4; ++r) {
      int m = m0 + quad * 4 + r;
      C[(long)m * N + n] = accs[j][r] * scale;
    }
  }
}

// Fused: scores + mask-log + log_softmax over s.
// decT: (B*T, L) fp32 pre-scaled by TANH_SCALE; encT: (B, L, S) fp32 pre-scaled;
// mask: (B,T,S); vt2: (L) = 2*vt; out: (B,T,S).
// Grid: B*T/2 blocks of 256 threads; block handles (b, t0, t0+1), thread = s.
__global__ __launch_bounds__(256) void fused_score_softmax(
    const float* __restrict__ decT, const float* __restrict__ encT,
    const float* __restrict__ mask, const float* __restrict__ vt2,
    float* __restrict__ out) {
  const int B = 8, T = 128, S = 256, L = 256;
  (void)B;
  const int blk = blockIdx.x;
  const int b = blk >> 6;            // 64 t-pairs per batch
  const int t0 = (blk & 63) * 2;
  const int s = threadIdx.x;

  const float* __restrict__ d0 = decT + (long)(b * T + t0) * L;
  const float* __restrict__ d1 = d0 + L;
  const float* __restrict__ ep = encT + (long)b * L * S + s;

  float acc0 = 0.f, acc1 = 0.f;
#pragma unroll 8
  for (int l = 0; l < L; ++l) {
    float e = ep[(long)l * S];
    float v = vt2[l];
    float r0 = __builtin_amdgcn_rcpf(__builtin_amdgcn_exp2f(d0[l] + e) + 1.0f);
    float r1 = __builtin_amdgcn_rcpf(__builtin_amdgcn_exp2f(d1[l] + e) + 1.0f);
    acc0 = fmaf(-v, r0, acc0);
    acc1 = fmaf(-v, r1, acc1);
  }

  // logits = (scores - const) + log(mask + eps)
  const float LN2 = 0.6931471805599453f, L2E = 1.4426950408889634f;
  float m0 = mask[(long)(b * T + t0) * S + s];
  float m1 = mask[(long)(b * T + t0 + 1) * S + s];
  float lg0 = acc0 + LN2 * __builtin_amdgcn_logf(m0 + 1e-8f);
  float lg1 = acc1 + LN2 * __builtin_amdgcn_logf(m1 + 1e-8f);

  // block max over s (wave butterfly + LDS across 4 waves)
  __shared__ float redm0[4], redm1[4], reds0[4], reds1[4];
  const int wid = threadIdx.x >> 6, lane = threadIdx.x & 63;
  float w0 = lg0, w1 = lg1;
#pragma unroll
  for (int off = 1; off < 64; off <<= 1) {
    w0 = fmaxf(w0, __shfl_xor(w0, off));
    w1 = fmaxf(w1, __shfl_xor(w1, off));
  }
  if (lane == 0) { redm0[wid] = w0; redm1[wid] = w1; }
  __syncthreads();
  float bm0 = fmaxf(fmaxf(redm0[0], redm0[1]), fmaxf(redm0[2], redm0[3]));
  float bm1 = fmaxf(fmaxf(redm1[0], redm1[1]), fmaxf(redm1[2], redm1[3]));

  float e0 = __builtin_amdgcn_exp2f((lg0 - bm0) * L2E);
  float e1 = __builtin_amdgcn_exp2f((lg1 - bm1) * L2E);
  float q0 = e0, q1 = e1;
#pragma unroll
  for (int off = 1; off < 64; off <<= 1) {
    q0 += __shfl_xor(q0, off);
    q1 += __shfl_xor(q1, off);
  }
  if (lane == 0) { reds0[wid] = q0; reds1[wid] = q1; }
  __syncthreads();
  float t0sum = reds0[0] + reds0[1] + reds0[2] + reds0[3];
  float t1sum = reds1[0] + reds1[1] + reds1[2] + reds1[3];

  out[(long)(b * T + t0) * S + s] = lg0 - bm0 - LN2 * __builtin_amdgcn_logf(t0sum);
  out[(long)(b * T + t0 + 1) * S + s] = lg1 - bm1 - LN2 * __builtin_amdgcn_logf(t1sum);
}

extern "C" void kernel_launch(void* const* d_in, const int* in_sizes, int n_in,
                              void* d_out, int out_size, void* d_ws, size_t ws_size,
                              hipStream_t stream) {
  const int B = 8, T = 128, S = 256, L = 256, D = 512;
  const float* dec = (const float*)d_in[0];   // (B,T,D)  524288
  const float* enc = (const float*)d_in[1];   // (B,S,D) 1048576
  const float* mask = (const float*)d_in[2];  // (B,T,S)  262144
  const float* W1 = (const float*)d_in[3];    // (L,D)    131072
  const float* W2 = (const float*)d_in[4];    // (L,D)    131072
  const float* vt = (const float*)d_in[5];    // (L)          256
  float* out = (float*)d_out;                 // (B,T,S)

  char* ws = (char*)d_ws;
  unsigned short* dec_b = (unsigned short*)(ws);                 // 1 MB
  unsigned short* enc_b = (unsigned short*)(ws + (1u << 20));    // 2 MB
  unsigned short* w1_b = (unsigned short*)(ws + 3 * (1u << 20));        // 256 KB
  unsigned short* w2_b = (unsigned short*)(ws + 3 * (1u << 20) + (256u << 10));
  float* vt2 = (float*)(ws + 3 * (1u << 20) + (512u << 10));     // 1 KB
  float* decT = (float*)(ws + 3 * (1u << 20) + (516u << 10));    // 1 MB
  float* encT = (float*)(ws + 4 * (1u << 20) + (516u << 10));    // 2 MB

  // fp32 -> bf16 conversions
  cvt_bf16x4<<<(B * T * D / 4 + 255) / 256, 256, 0, stream>>>((const float4*)dec, (ushort4*)dec_b, B * T * D / 4);
  cvt_bf16x4<<<(B * S * D / 4 + 255) / 256, 256, 0, stream>>>((const float4*)enc, (ushort4*)enc_b, B * S * D / 4);
  cvt_bf16x4<<<(L * D / 4 + 255) / 256, 256, 0, stream>>>((const float4*)W1, (ushort4*)w1_b, L * D / 4);
  cvt_bf16x4<<<(L * D / 4 + 255) / 256, 256, 0, stream>>>((const float4*)W2, (ushort4*)w2_b, L * D / 4);
  scale_vt<<<1, 256, 0, stream>>>(vt, vt2, L);

  // decT (B*T, L) = dec . W1^T, pre-scaled for the tanh->exp2 rewrite
  {
    dim3 g(B * T / 64, L / 64, 1);
    gemm_nt_bf16<<<g, 256, 0, stream>>>(dec_b, w1_b, decT, B * T, L, D, 0, 0, 0, TANH_SCALE);
  }
  // encT (B, L, S): per-batch C[l][s] = W2[l,:] . enc[b,s,:]  (A = W2, B = enc[b])
  {
    dim3 g(L / 64, S / 64, B);
    gemm_nt_bf16<<<g, 256, 0, stream>>>(w2_b, enc_b, encT, L, S, D,
                                        0, (long)S * D, (long)L * S, TANH_SCALE);
  }
  // fused scores + masked log-softmax
  fused_score_softmax<<<B * T / 2, 256, 0, stream>>>(decT, encT, mask, vt2, out);
}

// Round 2
// 105.510 us; speedup vs baseline: 1.1015x; 1.1015x over previous
//
#include <hip/hip_runtime.h>

typedef __attribute__((ext_vector_type(8))) short short8;
typedef __attribute__((ext_vector_type(4))) float f32x4;

#define TANH_SCALE 2.8853900817779268f  /* 2*log2(e): exp(2x) = exp2(x*TANH_SCALE) */

static __device__ __forceinline__ unsigned short f2bf(float f) {
  unsigned u = __builtin_bit_cast(unsigned, f);
  u += 0x7FFFu + ((u >> 16) & 1u);   // round-to-nearest-even
  return (unsigned short)(u >> 16);
}

// One launch converts all four fp32 tensors to bf16 (region-decoded by flat index).
// Region sizes in float4 units: dec 131072 | enc 262144 | W1 32768 | W2 32768.
__global__ __launch_bounds__(256) void cvt_all(
    const float4* __restrict__ dec, const float4* __restrict__ enc,
    const float4* __restrict__ W1, const float4* __restrict__ W2,
    ushort4* __restrict__ dec_b, ushort4* __restrict__ enc_b,
    ushort4* __restrict__ w1_b, ushort4* __restrict__ w2_b) {
  int i = blockIdx.x * 256 + threadIdx.x;
  const float4* src; ushort4* dst; int off;
  if (i < 131072)            { src = dec; dst = dec_b; off = 0; }
  else if (i < 131072+262144){ src = enc; dst = enc_b; off = 131072; }
  else if (i < 131072+262144+32768) { src = W1; dst = w1_b; off = 131072+262144; }
  else                       { src = W2; dst = w2_b; off = 131072+262144+32768; }
  int j = i - off;
  float4 v = src[j];
  ushort4 o;
  o.x = f2bf(v.x); o.y = f2bf(v.y); o.z = f2bf(v.z); o.w = f2bf(v.w);
  dst[j] = o;
}

// Combined NT GEMM for both projections, with exp2(TANH_SCALE*x) epilogue.
//   blocks [0,64):   decPt(256x1024) = exp2(c * W1(256x512) . dec(1024x512)^T)
//   blocks [64,192): encP (8,256,256) = exp2(c * W2(256x512) . enc_b(256x512)^T) per batch
// K = 512 fixed. Block = 4 waves; wave w: rows [m0+16w,m0+16w+16) x cols [n0,n0+64).
__global__ __launch_bounds__(256) void gemm_proj(
    const unsigned short* __restrict__ w1b, const unsigned short* __restrict__ w2b,
    const unsigned short* __restrict__ decb, const unsigned short* __restrict__ encb,
    float* __restrict__ decPt, float* __restrict__ encP) {
  const int K = 512;
  int idx = blockIdx.x;
  const unsigned short *A, *Bp;
  float* C;
  int N, mt, nt;
  if (idx < 64) {
    A = w1b; Bp = decb; C = decPt; N = 1024;
    mt = idx >> 4; nt = idx & 15;
  } else {
    int j = idx - 64, z = j >> 4;
    A = w2b; Bp = encb + (size_t)z * 256 * K; C = encP + (size_t)z * 256 * 256; N = 256;
    mt = (j >> 2) & 3; nt = j & 3;
  }
  const int tid = threadIdx.x, wave = tid >> 6, lane = tid & 63;
  const int m0 = mt * 64 + wave * 16;
  const int n0 = nt * 64;
  const int l16 = lane & 15, quad = lane >> 4, kb = quad * 8;

  f32x4 acc0 = {0.f,0.f,0.f,0.f}, acc1 = {0.f,0.f,0.f,0.f};
  f32x4 acc2 = {0.f,0.f,0.f,0.f}, acc3 = {0.f,0.f,0.f,0.f};

  const unsigned short* ap  = A + (long)(m0 + l16) * K + kb;
  const unsigned short* bp0 = Bp + (long)(n0 + l16) * K + kb;

  for (int ks = 0; ks < K; ks += 32) {
    short8 a  = *(const short8*)(ap + ks);
    short8 b0 = *(const short8*)(bp0 + ks);
    short8 b1 = *(const short8*)(bp0 + 16 * K + ks);
    short8 b2 = *(const short8*)(bp0 + 32 * K + ks);
    short8 b3 = *(const short8*)(bp0 + 48 * K + ks);
    acc0 = __builtin_amdgcn_mfma_f32_16x16x32_bf16(a, b0, acc0, 0, 0, 0);
    acc1 = __builtin_amdgcn_mfma_f32_16x16x32_bf16(a, b1, acc1, 0, 0, 0);
    acc2 = __builtin_amdgcn_mfma_f32_16x16x32_bf16(a, b2, acc2, 0, 0, 0);
    acc3 = __builtin_amdgcn_mfma_f32_16x16x32_bf16(a, b3, acc3, 0, 0, 0);
  }

  // C/D layout: col = lane&15, row = quad*4 + reg. Store exp2(c*acc), coalesced in n.
  f32x4 accs[4] = {acc0, acc1, acc2, acc3};
#pragma unroll
  for (int j = 0; j < 4; ++j) {
    int n = n0 + j * 16 + l16;
#pragma unroll
    for (int r = 0; r < 4; ++r) {
      int m = m0 + quad * 4 + r;
      C[(long)m * N + n] = __builtin_amdgcn_exp2f(accs[j][r] * TANH_SCALE);
    }
  }
}

// Fused scores + masked log-softmax.
//   scores = -2 * sum_l vt[l] * rcp(P[t][l]*E[s][l] + 1)   (+ softmax-invariant const, dropped)
// decPt: (L=256, BT=1024) = exp2(c*dec_t) transposed; encP: (B,L,S) = exp2(c*enc_t);
// Block = 256 threads (thread = s), handles 4 consecutive t. Grid = B*T/4 = 256.
__global__ __launch_bounds__(256) void fused_score_softmax(
    const float* __restrict__ decPt, const float* __restrict__ encP,
    const float* __restrict__ mask, const float* __restrict__ vt,
    float* __restrict__ out) {
  const int T = 128, S = 256, L = 256;
  const int b = blockIdx.x >> 5;
  const int t0 = (blockIdx.x & 31) * 4;
  const int s = threadIdx.x;

  const float* __restrict__ ep = encP + (size_t)b * L * S + s;   // + l*S
  const float* __restrict__ dp = decPt + (size_t)(b * T + t0);   // + l*1024, float4, uniform

  float acc0 = 0.f, acc1 = 0.f, acc2 = 0.f, acc3 = 0.f;
#pragma unroll 8
  for (int l = 0; l < L; ++l) {
    float e = ep[(size_t)l * S];
    float4 P = *(const float4*)(dp + (size_t)l * 1024);
    float v = vt[l];
    float r0 = __builtin_amdgcn_rcpf(fmaf(P.x, e, 1.0f));
    float r1 = __builtin_amdgcn_rcpf(fmaf(P.y, e, 1.0f));
    float r2 = __builtin_amdgcn_rcpf(fmaf(P.z, e, 1.0f));
    float r3 = __builtin_amdgcn_rcpf(fmaf(P.w, e, 1.0f));
    acc0 = fmaf(v, r0, acc0);
    acc1 = fmaf(v, r1, acc1);
    acc2 = fmaf(v, r2, acc2);
    acc3 = fmaf(v, r3, acc3);
  }

  const float LN2 = 0.6931471805599453f, L2E = 1.4426950408889634f;
  float lg[4] = {acc0, acc1, acc2, acc3};
#pragma unroll
  for (int i = 0; i < 4; ++i) {
    float m = mask[(size_t)(b * T + t0 + i) * S + s];
    lg[i] = fmaf(-2.0f, lg[i], LN2 * __builtin_amdgcn_logf(m + 1e-8f));
  }

  __shared__ float redm[4][4], reds[4][4];
  const int wid = threadIdx.x >> 6, lane = threadIdx.x & 63;

  float w[4] = {lg[0], lg[1], lg[2], lg[3]};
#pragma unroll
  for (int off = 1; off < 64; off <<= 1)
#pragma unroll
    for (int i = 0; i < 4; ++i) w[i] = fmaxf(w[i], __shfl_xor(w[i], off));
  if (lane == 0)
#pragma unroll
    for (int i = 0; i < 4; ++i) redm[wid][i] = w[i];
  __syncthreads();
  float bm[4];
#pragma unroll
  for (int i = 0; i < 4; ++i)
    bm[i] = fmaxf(fmaxf(redm[0][i], redm[1][i]), fmaxf(redm[2][i], redm[3][i]));

  float q[4];
#pragma unroll
  for (int i = 0; i < 4; ++i) q[i] = __builtin_amdgcn_exp2f((lg[i] - bm[i]) * L2E);
#pragma unroll
  for (int off = 1; off < 64; off <<= 1)
#pragma unroll
    for (int i = 0; i < 4; ++i) q[i] += __shfl_xor(q[i], off);
  if (lane == 0)
#pragma unroll
    for (int i = 0; i < 4; ++i) reds[wid][i] = q[i];
  __syncthreads();

#pragma unroll
  for (int i = 0; i < 4; ++i) {
    float sum = reds[0][i] + reds[1][i] + reds[2][i] + reds[3][i];
    out[(size_t)(b * T + t0 + i) * S + s] = lg[i] - bm[i] - LN2 * __builtin_amdgcn_logf(sum);
  }
}

extern "C" void kernel_launch(void* const* d_in, const int* in_sizes, int n_in,
                              void* d_out, int out_size, void* d_ws, size_t ws_size,
                              hipStream_t stream) {
  const int B = 8, T = 128, S = 256, L = 256, D = 512;
  const float* dec = (const float*)d_in[0];   // (B,T,D)
  const float* enc = (const float*)d_in[1];   // (B,S,D)
  const float* mask = (const float*)d_in[2];  // (B,T,S)
  const float* W1 = (const float*)d_in[3];    // (L,D)
  const float* W2 = (const float*)d_in[4];    // (L,D)
  const float* vt = (const float*)d_in[5];    // (L)
  float* out = (float*)d_out;                 // (B,T,S)

  char* ws = (char*)d_ws;
  unsigned short* dec_b = (unsigned short*)(ws);                     // 1 MB
  unsigned short* enc_b = (unsigned short*)(ws + (1u << 20));        // 2 MB
  unsigned short* w1_b  = (unsigned short*)(ws + 3u * (1u << 20));   // 256 KB
  unsigned short* w2_b  = (unsigned short*)(ws + 3u * (1u << 20) + (256u << 10));
  float* decPt = (float*)(ws + 3u * (1u << 20) + (512u << 10));      // 1 MB (L x BT)
  float* encP  = (float*)(ws + 4u * (1u << 20) + (512u << 10));      // 2 MB (B,L,S)

  // 1) all fp32->bf16 conversions in one launch
  cvt_all<<<1792, 256, 0, stream>>>(
      (const float4*)dec, (const float4*)enc, (const float4*)W1, (const float4*)W2,
      (ushort4*)dec_b, (ushort4*)enc_b, (ushort4*)w1_b, (ushort4*)w2_b);

  // 2) both projections + exp2 epilogue in one launch
  gemm_proj<<<192, 256, 0, stream>>>(w1_b, w2_b, dec_b, enc_b, decPt, encP);

  // 3) fused scores + masked log-softmax
  fused_score_softmax<<<B * T / 4, 256, 0, stream>>>(decPt, encP, mask, vt, out);
  (void)in_sizes; (void)n_in; (void)out_size; (void)ws_size; (void)D;
}

// Round 3
// 98.515 us; speedup vs baseline: 1.1797x; 1.0710x over previous
//
#include <hip/hip_runtime.h>

typedef __attribute__((ext_vector_type(8))) short short8;
typedef __attribute__((ext_vector_type(4))) float f32x4;

#define TANH_SCALE 2.8853900817779268f  /* 2*log2(e): exp(2x) = exp2(x*TANH_SCALE) */
#define LOG_EPS   -18.420680743952367f  /* log(1e-8f): exact masked-out additive */

static __device__ __forceinline__ unsigned short f2bf(float f) {
  unsigned u = __builtin_bit_cast(unsigned, f);
  u += 0x7FFFu + ((u >> 16) & 1u);   // round-to-nearest-even
  return (unsigned short)(u >> 16);
}

// One launch converts all four fp32 tensors to bf16 (region-decoded by flat index).
// Region sizes in float4 units: dec 131072 | enc 262144 | W1 32768 | W2 32768.
__global__ __launch_bounds__(256) void cvt_all(
    const float4* __restrict__ dec, const float4* __restrict__ enc,
    const float4* __restrict__ W1, const float4* __restrict__ W2,
    ushort4* __restrict__ dec_b, ushort4* __restrict__ enc_b,
    ushort4* __restrict__ w1_b, ushort4* __restrict__ w2_b) {
  int i = blockIdx.x * 256 + threadIdx.x;
  const float4* src; ushort4* dst; int off;
  if (i < 131072)            { src = dec; dst = dec_b; off = 0; }
  else if (i < 131072+262144){ src = enc; dst = enc_b; off = 131072; }
  else if (i < 131072+262144+32768) { src = W1; dst = w1_b; off = 131072+262144; }
  else                       { src = W2; dst = w2_b; off = 131072+262144+32768; }
  int j = i - off;
  float4 v = src[j];
  ushort4 o;
  o.x = f2bf(v.x); o.y = f2bf(v.y); o.z = f2bf(v.z); o.w = f2bf(v.w);
  dst[j] = o;
}

// Combined NT GEMM for both projections with exp2(TANH_SCALE*x) epilogue.
// Wave tile 16x32 (2 MFMA/k-step) for TLP: 1536 waves total (~1.5/SIMD).
//   blocks [0,128):   decPt(256x1024) = exp2(c * W1 . dec^T)      mt=idx>>5, nt=idx&31
//   blocks [128,384): encP (8,256,256) = exp2(c * W2 . enc_b^T)   per batch z
// K = 512. Block = 4 waves stacked on M; wave w: rows [m0+16w,+16) x cols [n0,n0+32).
__global__ __launch_bounds__(256) void gemm_proj(
    const unsigned short* __restrict__ w1b, const unsigned short* __restrict__ w2b,
    const unsigned short* __restrict__ decb, const unsigned short* __restrict__ encb,
    float* __restrict__ decPt, float* __restrict__ encP) {
  const int K = 512;
  int idx = blockIdx.x;
  const unsigned short *A, *Bp;
  float* C;
  int N, mt, nt;
  if (idx < 128) {
    A = w1b; Bp = decb; C = decPt; N = 1024;
    mt = idx >> 5; nt = idx & 31;
  } else {
    int j = idx - 128, z = j >> 5, rem = j & 31;
    A = w2b; Bp = encb + (size_t)z * 256 * K; C = encP + (size_t)z * 256 * 256; N = 256;
    mt = rem >> 3; nt = rem & 7;
  }
  const int tid = threadIdx.x, wave = tid >> 6, lane = tid & 63;
  const int m0 = mt * 64 + wave * 16;
  const int n0 = nt * 32;
  const int l16 = lane & 15, quad = lane >> 4, kb = quad * 8;

  f32x4 acc0 = {0.f,0.f,0.f,0.f}, acc1 = {0.f,0.f,0.f,0.f};

  const unsigned short* ap  = A + (long)(m0 + l16) * K + kb;
  const unsigned short* bp0 = Bp + (long)(n0 + l16) * K + kb;

  for (int ks = 0; ks < K; ks += 32) {
    short8 a  = *(const short8*)(ap + ks);
    short8 b0 = *(const short8*)(bp0 + ks);
    short8 b1 = *(const short8*)(bp0 + 16 * K + ks);
    acc0 = __builtin_amdgcn_mfma_f32_16x16x32_bf16(a, b0, acc0, 0, 0, 0);
    acc1 = __builtin_amdgcn_mfma_f32_16x16x32_bf16(a, b1, acc1, 0, 0, 0);
  }

  // C/D layout: col = lane&15, row = quad*4 + reg. Store exp2(c*acc), coalesced in n.
  f32x4 accs[2] = {acc0, acc1};
#pragma unroll
  for (int j = 0; j < 2; ++j) {
    int n = n0 + j * 16 + l16;
#pragma unroll
    for (int r = 0; r < 4; ++r) {
      int m = m0 + quad * 4 + r;
      C[(long)m * N + n] = __builtin_amdgcn_exp2f(accs[j][r] * TANH_SCALE);
    }
  }
}

// Fused scores + masked log-softmax.
//   scores = -2 * sum_l vt[l] * rcp(P[t][l]*E[s][l] + 1)  (+ softmax-invariant const, dropped)
// decPt: (L=256, BT=1024) transposed exp2-form; encP: (B,L,S) exp2-form.
// Block = 512 threads: s = tid&255, half = tid>>8 handles l in [half*128, half*128+128).
// Block covers 4 consecutive t. Grid = B*T/4 = 256 blocks -> 2048 waves (2/SIMD).
__global__ __launch_bounds__(512) void fused_score_softmax(
    const float* __restrict__ decPt, const float* __restrict__ encP,
    const float* __restrict__ mask, const float* __restrict__ vt,
    float* __restrict__ out) {
  const int T = 128, S = 256, L = 256;
  const int b = blockIdx.x >> 5;
  const int t0 = (blockIdx.x & 31) * 4;
  const int s = threadIdx.x & 255;
  const int half = threadIdx.x >> 8;
  const int l0 = half * (L / 2);

  const float* __restrict__ ep = encP + (size_t)b * L * S + (size_t)l0 * S + s;
  const float* __restrict__ dp = decPt + (size_t)(b * T + t0) + (size_t)l0 * 1024;

  float acc0 = 0.f, acc1 = 0.f, acc2 = 0.f, acc3 = 0.f;
#pragma unroll 8
  for (int l = 0; l < L / 2; ++l) {
    float e = ep[(size_t)l * S];
    float4 P = *(const float4*)(dp + (size_t)l * 1024);
    float v = vt[l0 + l];
    float r0 = __builtin_amdgcn_rcpf(fmaf(P.x, e, 1.0f));
    float r1 = __builtin_amdgcn_rcpf(fmaf(P.y, e, 1.0f));
    float r2 = __builtin_amdgcn_rcpf(fmaf(P.z, e, 1.0f));
    float r3 = __builtin_amdgcn_rcpf(fmaf(P.w, e, 1.0f));
    acc0 = fmaf(v, r0, acc0);
    acc1 = fmaf(v, r1, acc1);
    acc2 = fmaf(v, r2, acc2);
    acc3 = fmaf(v, r3, acc3);
  }

  // combine the two l-halves via LDS
  __shared__ float partial[4][256];
  if (half == 1) {
    partial[0][s] = acc0; partial[1][s] = acc1;
    partial[2][s] = acc2; partial[3][s] = acc3;
  }
  __syncthreads();

  const float LN2 = 0.6931471805599453f, L2E = 1.4426950408889634f;
  __shared__ float redm[4][4], reds[4][4];
  const int wid = threadIdx.x >> 6, lane = threadIdx.x & 63;

  float lg[4];
  if (half == 0) {
    lg[0] = acc0 + partial[0][s];
    lg[1] = acc1 + partial[1][s];
    lg[2] = acc2 + partial[2][s];
    lg[3] = acc3 + partial[3][s];
    // logits: mask is exactly 0.0 or 1.0, and 1.0f+1e-8f == 1.0f in fp32, so
    // log(mask+eps) is exactly (mask != 0 ? 0 : log(1e-8f)).
#pragma unroll
    for (int i = 0; i < 4; ++i) {
      float m = mask[(size_t)(b * T + t0 + i) * S + s];
      lg[i] = fmaf(-2.0f, lg[i], (m != 0.0f) ? 0.0f : LOG_EPS);
    }
  } else {
    lg[0] = lg[1] = lg[2] = lg[3] = 0.f;  // inert lanes
  }

  // block max over s: wave butterfly + LDS across the 4 half-0 waves
  float w[4] = {lg[0], lg[1], lg[2], lg[3]};
#pragma unroll
  for (int off = 1; off < 64; off <<= 1)
#pragma unroll
    for (int i = 0; i < 4; ++i) w[i] = fmaxf(w[i], __shfl_xor(w[i], off));
  if (half == 0 && lane == 0)
#pragma unroll
    for (int i = 0; i < 4; ++i) redm[wid][i] = w[i];
  __syncthreads();
  float bm[4];
#pragma unroll
  for (int i = 0; i < 4; ++i)
    bm[i] = fmaxf(fmaxf(redm[0][i], redm[1][i]), fmaxf(redm[2][i], redm[3][i]));

  float q[4];
#pragma unroll
  for (int i = 0; i < 4; ++i) q[i] = __builtin_amdgcn_exp2f((lg[i] - bm[i]) * L2E);
#pragma unroll
  for (int off = 1; off < 64; off <<= 1)
#pragma unroll
    for (int i = 0; i < 4; ++i) q[i] += __shfl_xor(q[i], off);
  if (half == 0 && lane == 0)
#pragma unroll
    for (int i = 0; i < 4; ++i) reds[wid][i] = q[i];
  __syncthreads();

  if (half == 0) {
#pragma unroll
    for (int i = 0; i < 4; ++i) {
      float sum = reds[0][i] + reds[1][i] + reds[2][i] + reds[3][i];
      out[(size_t)(b * T + t0 + i) * S + s] = lg[i] - bm[i] - LN2 * __builtin_amdgcn_logf(sum);
    }
  }
}

extern "C" void kernel_launch(void* const* d_in, const int* in_sizes, int n_in,
                              void* d_out, int out_size, void* d_ws, size_t ws_size,
                              hipStream_t stream) {
  const int B = 8, T = 128, S = 256, L = 256, D = 512;
  const float* dec = (const float*)d_in[0];   // (B,T,D)
  const float* enc = (const float*)d_in[1];   // (B,S,D)
  const float* mask = (const float*)d_in[2];  // (B,T,S)
  const float* W1 = (const float*)d_in[3];    // (L,D)
  const float* W2 = (const float*)d_in[4];    // (L,D)
  const float* vt = (const float*)d_in[5];    // (L)
  float* out = (float*)d_out;                 // (B,T,S)

  char* ws = (char*)d_ws;
  unsigned short* dec_b = (unsigned short*)(ws);                     // 1 MB
  unsigned short* enc_b = (unsigned short*)(ws + (1u << 20));        // 2 MB
  unsigned short* w1_b  = (unsigned short*)(ws + 3u * (1u << 20));   // 256 KB
  unsigned short* w2_b  = (unsigned short*)(ws + 3u * (1u << 20) + (256u << 10));
  float* decPt = (float*)(ws + 3u * (1u << 20) + (512u << 10));      // 1 MB (L x BT)
  float* encP  = (float*)(ws + 4u * (1u << 20) + (512u << 10));      // 2 MB (B,L,S)

  // 1) all fp32->bf16 conversions in one launch
  cvt_all<<<1792, 256, 0, stream>>>(
      (const float4*)dec, (const float4*)enc, (const float4*)W1, (const float4*)W2,
      (ushort4*)dec_b, (ushort4*)enc_b, (ushort4*)w1_b, (ushort4*)w2_b);

  // 2) both projections + exp2 epilogue in one launch (384 blocks, 1536 waves)
  gemm_proj<<<384, 256, 0, stream>>>(w1_b, w2_b, dec_b, enc_b, decPt, encP);

  // 3) fused scores + masked log-softmax (256 blocks x 512 threads, 2048 waves)
  fused_score_softmax<<<B * T / 4, 512, 0, stream>>>(decPt, encP, mask, vt, out);
  (void)in_sizes; (void)n_in; (void)out_size; (void)ws_size; (void)D;
}

// Round 4
// 97.390 us; speedup vs baseline: 1.1934x; 1.0115x over previous
//
#include <hip/hip_runtime.h>

typedef __attribute__((ext_vector_type(8))) short short8;
typedef __attribute__((ext_vector_type(4))) float f32x4;

#define TANH_SCALE 2.8853900817779268f  /* 2*log2(e): exp(2x) = exp2(x*TANH_SCALE) */
#define LOG_EPS   -18.420680743952367f  /* log(1e-8f): exact masked-out additive */

static __device__ __forceinline__ unsigned short f2bf(float f) {
  unsigned u = __builtin_bit_cast(unsigned, f);
  u += 0x7FFFu + ((u >> 16) & 1u);   // round-to-nearest-even
  return (unsigned short)(u >> 16);
}
static __device__ __forceinline__ float bf2f(unsigned short h) {
  unsigned u = (unsigned)h << 16;
  return __builtin_bit_cast(float, u);
}

// One launch converts all four fp32 tensors to bf16 (region-decoded by flat index).
// Region sizes in float4 units: dec 131072 | enc 262144 | W1 32768 | W2 32768.
__global__ __launch_bounds__(256) void cvt_all(
    const float4* __restrict__ dec, const float4* __restrict__ enc,
    const float4* __restrict__ W1, const float4* __restrict__ W2,
    ushort4* __restrict__ dec_b, ushort4* __restrict__ enc_b,
    ushort4* __restrict__ w1_b, ushort4* __restrict__ w2_b) {
  int i = blockIdx.x * 256 + threadIdx.x;
  const float4* src; ushort4* dst; int off;
  if (i < 131072)            { src = dec; dst = dec_b; off = 0; }
  else if (i < 131072+262144){ src = enc; dst = enc_b; off = 131072; }
  else if (i < 131072+262144+32768) { src = W1; dst = w1_b; off = 131072+262144; }
  else                       { src = W2; dst = w2_b; off = 131072+262144+32768; }
  int j = i - off;
  float4 v = src[j];
  ushort4 o;
  o.x = f2bf(v.x); o.y = f2bf(v.y); o.z = f2bf(v.z); o.w = f2bf(v.w);
  dst[j] = o;
}

// Combined NT GEMM for both projections with exp2(TANH_SCALE*x) epilogue.
// Wave tile 16x32 (2 MFMA/k-step): 1536 waves (~1.5/SIMD, 1.5 blocks/CU).
//   blocks [0,128):   decPt(256x1024) fp32 = exp2(c * W1 . dec^T)
//   blocks [128,384): encPb(8,256,256) BF16 = exp2(c * W2 . enc_b^T) per batch
// K = 512. Block = 4 waves stacked on M; wave w: rows [m0+16w,+16) x cols [n0,n0+32).
__global__ __launch_bounds__(256) void gemm_proj(
    const unsigned short* __restrict__ w1b, const unsigned short* __restrict__ w2b,
    const unsigned short* __restrict__ decb, const unsigned short* __restrict__ encb,
    float* __restrict__ decPt, unsigned short* __restrict__ encPb) {
  const int K = 512;
  int idx = blockIdx.x;
  const unsigned short *A, *Bp;
  int N, mt, nt;
  bool is_dec = (idx < 128);
  size_t cbase;
  if (is_dec) {
    A = w1b; Bp = decb; N = 1024;
    mt = idx >> 5; nt = idx & 31;
    cbase = 0;
  } else {
    int j = idx - 128, z = j >> 5, rem = j & 31;
    A = w2b; Bp = encb + (size_t)z * 256 * K; N = 256;
    mt = rem >> 3; nt = rem & 7;
    cbase = (size_t)z * 256 * 256;
  }
  const int tid = threadIdx.x, wave = tid >> 6, lane = tid & 63;
  const int m0 = mt * 64 + wave * 16;
  const int n0 = nt * 32;
  const int l16 = lane & 15, quad = lane >> 4, kb = quad * 8;

  f32x4 acc0 = {0.f,0.f,0.f,0.f}, acc1 = {0.f,0.f,0.f,0.f};

  const unsigned short* ap  = A + (long)(m0 + l16) * K + kb;
  const unsigned short* bp0 = Bp + (long)(n0 + l16) * K + kb;

  for (int ks = 0; ks < K; ks += 32) {
    short8 a  = *(const short8*)(ap + ks);
    short8 b0 = *(const short8*)(bp0 + ks);
    short8 b1 = *(const short8*)(bp0 + 16 * K + ks);
    acc0 = __builtin_amdgcn_mfma_f32_16x16x32_bf16(a, b0, acc0, 0, 0, 0);
    acc1 = __builtin_amdgcn_mfma_f32_16x16x32_bf16(a, b1, acc1, 0, 0, 0);
  }

  // C/D layout: col = lane&15, row = quad*4 + reg. Store exp2(c*acc), coalesced in n.
  f32x4 accs[2] = {acc0, acc1};
  if (is_dec) {
#pragma unroll
    for (int j = 0; j < 2; ++j) {
      int n = n0 + j * 16 + l16;
#pragma unroll
      for (int r = 0; r < 4; ++r) {
        int m = m0 + quad * 4 + r;
        decPt[(long)m * N + n] = __builtin_amdgcn_exp2f(accs[j][r] * TANH_SCALE);
      }
    }
  } else {
#pragma unroll
    for (int j = 0; j < 2; ++j) {
      int n = n0 + j * 16 + l16;
#pragma unroll
      for (int r = 0; r < 4; ++r) {
        int m = m0 + quad * 4 + r;
        encPb[cbase + (long)m * N + n] =
            f2bf(__builtin_amdgcn_exp2f(accs[j][r] * TANH_SCALE));
      }
    }
  }
}

// Fused scores + masked log-softmax.
//   scores = -2 * sum_l vt[l] * rcp(P[t][l]*E[s][l] + 1)  (+ softmax-invariant const, dropped)
// decPt: (L=256, BT=1024) fp32 transposed exp2-form; encPb: (B,L,S) bf16 exp2-form.
// Block = 1024 threads: s = tid&255, quarter q = tid>>8 does l in [64q, 64q+64).
// Block covers 4 consecutive t; epilogue: quarter q owns softmax of row t0+q.
// Grid = B*T/4 = 256 blocks x 16 waves -> 4 waves/SIMD, 1 block/CU.
__global__ __launch_bounds__(1024) void fused_score_softmax(
    const float* __restrict__ decPt, const unsigned short* __restrict__ encPb,
    const float* __restrict__ mask, const float* __restrict__ vt,
    float* __restrict__ out) {
  const int T = 128, S = 256, L = 256;
  const int b = blockIdx.x >> 5;
  const int t0 = (blockIdx.x & 31) * 4;
  const int s = threadIdx.x & 255;
  const int q = threadIdx.x >> 8;
  const int l0 = q * (L / 4);

  const unsigned short* __restrict__ ep = encPb + (size_t)b * L * S + (size_t)l0 * S + s;
  const float* __restrict__ dp = decPt + (size_t)(b * T + t0) + (size_t)l0 * 1024;

  float acc0 = 0.f, acc1 = 0.f, acc2 = 0.f, acc3 = 0.f;
#pragma unroll 8
  for (int l = 0; l < L / 4; ++l) {
    float e = bf2f(ep[(size_t)l * S]);
    float4 P = *(const float4*)(dp + (size_t)l * 1024);   // wave-uniform -> s_load
    float v = vt[l0 + l];
    float r0 = __builtin_amdgcn_rcpf(fmaf(P.x, e, 1.0f));
    float r1 = __builtin_amdgcn_rcpf(fmaf(P.y, e, 1.0f));
    float r2 = __builtin_amdgcn_rcpf(fmaf(P.z, e, 1.0f));
    float r3 = __builtin_amdgcn_rcpf(fmaf(P.w, e, 1.0f));
    acc0 = fmaf(v, r0, acc0);
    acc1 = fmaf(v, r1, acc1);
    acc2 = fmaf(v, r2, acc2);
    acc3 = fmaf(v, r3, acc3);
  }

  // combine l-quarters: everyone writes, then quarter q owns row t0+q
  __shared__ float partial[4][4][256];   // [quarter][t][s]
  partial[q][0][s] = acc0;
  partial[q][1][s] = acc1;
  partial[q][2][s] = acc2;
  partial[q][3][s] = acc3;
  __syncthreads();

  float lg = partial[0][q][s] + partial[1][q][s] + partial[2][q][s] + partial[3][q][s];

  // logits: mask is exactly 0.0 or 1.0, and 1.0f + 1e-8f == 1.0f in fp32,
  // so log(mask+eps) == (mask != 0 ? 0 : log(1e-8f)) exactly.
  const float LN2 = 0.6931471805599453f, L2E = 1.4426950408889634f;
  {
    float m = mask[(size_t)(b * T + t0 + q) * S + s];
    lg = fmaf(-2.0f, lg, (m != 0.0f) ? 0.0f : LOG_EPS);
  }

  // softmax over s (256 wide = the 4 waves of this quarter)
  __shared__ float redm[16], reds[16];
  const int wid = threadIdx.x >> 6, lane = threadIdx.x & 63;

  float w = lg;
#pragma unroll
  for (int off = 1; off < 64; off <<= 1) w = fmaxf(w, __shfl_xor(w, off));
  if (lane == 0) redm[wid] = w;
  __syncthreads();
  float bm = fmaxf(fmaxf(redm[q * 4 + 0], redm[q * 4 + 1]),
                   fmaxf(redm[q * 4 + 2], redm[q * 4 + 3]));

  float e = __builtin_amdgcn_exp2f((lg - bm) * L2E);
#pragma unroll
  for (int off = 1; off < 64; off <<= 1) e += __shfl_xor(e, off);
  if (lane == 0) reds[wid] = e;
  __syncthreads();
  float sum = reds[q * 4 + 0] + reds[q * 4 + 1] + reds[q * 4 + 2] + reds[q * 4 + 3];

  out[(size_t)(b * T + t0 + q) * S + s] = lg - bm - LN2 * __builtin_amdgcn_logf(sum);
}

extern "C" void kernel_launch(void* const* d_in, const int* in_sizes, int n_in,
                              void* d_out, int out_size, void* d_ws, size_t ws_size,
                              hipStream_t stream) {
  const int B = 8, T = 128, S = 256, L = 256, D = 512;
  const float* dec = (const float*)d_in[0];   // (B,T,D)
  const float* enc = (const float*)d_in[1];   // (B,S,D)
  const float* mask = (const float*)d_in[2];  // (B,T,S)
  const float* W1 = (const float*)d_in[3];    // (L,D)
  const float* W2 = (const float*)d_in[4];    // (L,D)
  const float* vt = (const float*)d_in[5];    // (L)
  float* out = (float*)d_out;                 // (B,T,S)

  char* ws = (char*)d_ws;
  unsigned short* dec_b = (unsigned short*)(ws);                     // 1 MB
  unsigned short* enc_b = (unsigned short*)(ws + (1u << 20));        // 2 MB
  unsigned short* w1_b  = (unsigned short*)(ws + 3u * (1u << 20));   // 256 KB
  unsigned short* w2_b  = (unsigned short*)(ws + 3u * (1u << 20) + (256u << 10));
  float* decPt = (float*)(ws + 3u * (1u << 20) + (512u << 10));      // 1 MB (L x BT) fp32
  unsigned short* encPb = (unsigned short*)(ws + 4u * (1u << 20) + (512u << 10)); // 1 MB bf16

  // 1) all fp32->bf16 conversions in one launch
  cvt_all<<<1792, 256, 0, stream>>>(
      (const float4*)dec, (const float4*)enc, (const float4*)W1, (const float4*)W2,
      (ushort4*)dec_b, (ushort4*)enc_b, (ushort4*)w1_b, (ushort4*)w2_b);

  // 2) both projections + exp2 epilogue in one launch (384 blocks, 1536 waves)
  gemm_proj<<<384, 256, 0, stream>>>(w1_b, w2_b, dec_b, enc_b, decPt, encPb);

  // 3) fused scores + masked log-softmax (256 blocks x 1024 threads, 4096 waves)
  fused_score_softmax<<<B * T / 4, 1024, 0, stream>>>(decPt, encPb, mask, vt, out);
  (void)in_sizes; (void)n_in; (void)out_size; (void)ws_size; (void)D;
}